// Round 1
// baseline (13.446 us; speedup 1.0000x reference)
//
#include <hip/hip_runtime.h>

// OriginalConjunctionLayer: res_bar[b,n] = prod_d (1 - (1-x[b,d]) * (W[d,n] > 0.5))
//                          = prod_{d : W[d,n] > 0.5} x[b,d]
// m_out = ones. W in [0,0.5) with this data -> all mask bits zero -> output all 1.0,
// but the kernel is correct for arbitrary W via the per-bit slow path.

#define DDIM 1024   // input dim
#define NRULE 64    // rule nodes (== wave size, lane = n)
#define WPN (DDIM / 32)  // 32 mask words per column

// Kernel 1: binarize W (D,N) row-major into packed bitmasks bm[w*64 + n],
// bit j of bm[w*64+n] = (W[(w*32+j)*N + n] > 0.5f).
__global__ void __launch_bounds__(256) binarize_pack_kernel(
    const float* __restrict__ W, unsigned* __restrict__ bm) {
    int t = blockIdx.x * blockDim.x + threadIdx.x;   // 2048 threads total
    int n = t & (NRULE - 1);
    int w = t >> 6;
    if (w >= WPN) return;
    unsigned word = 0u;
    #pragma unroll
    for (int j = 0; j < 32; ++j) {
        int d = w * 32 + j;
        // lanes span n -> 64 consecutive floats per load: fully coalesced
        word |= (W[d * NRULE + n] > 0.5f) ? (1u << j) : 0u;
    }
    bm[w * NRULE + n] = word;   // t-contiguous: coalesced store
}

// Kernel 2: one wave per batch row b, lane = n. Stage the 8KB bitmask into LDS
// once per block; per 32-d chunk, skip x entirely if no lane has a set bit.
__global__ void __launch_bounds__(256) conj_forward_kernel(
    const float* __restrict__ x, const unsigned* __restrict__ bm,
    float* __restrict__ out, int B) {
    __shared__ unsigned bm_lds[WPN * NRULE];   // 2048 words = 8 KB

    int tid = threadIdx.x;
    {   // 2048 words / 256 threads = 2 x uint4 per thread, coalesced
        const uint4* src = reinterpret_cast<const uint4*>(bm);
        uint4* dst = reinterpret_cast<uint4*>(bm_lds);
        dst[tid]       = src[tid];
        dst[tid + 256] = src[tid + 256];
    }
    __syncthreads();

    int wave = tid >> 6;
    int lane = tid & 63;                // lane = n
    int b = blockIdx.x * 4 + wave;
    if (b >= B) return;

    const float* xrow = x + (size_t)b * DDIM;
    float acc = 1.0f;

    for (int w = 0; w < WPN; ++w) {
        // layout bm_lds[w*64 + n]: bank = n % 32 -> 2-way (free) LDS access
        unsigned word = bm_lds[w * NRULE + lane];
        if (__any(word != 0u)) {
            // Slow path (only for chunks with at least one set bit anywhere in
            // the wave): multiply in x values where this lane's bits are set.
            #pragma unroll
            for (int j = 0; j < 32; j += 4) {
                float4 xv = *reinterpret_cast<const float4*>(xrow + w * 32 + j);
                if (word & (1u << (j + 0))) acc *= xv.x;
                if (word & (1u << (j + 1))) acc *= xv.y;
                if (word & (1u << (j + 2))) acc *= xv.z;
                if (word & (1u << (j + 3))) acc *= xv.w;
            }
        }
        // word == 0 across wave -> factor chunk is all 1.0: skip loads + mults
    }

    size_t o = (size_t)b * NRULE + lane;
    out[o] = acc;                          // res_bar, coalesced
    out[(size_t)B * NRULE + o] = 1.0f;     // m_out = ones, coalesced
}

extern "C" void kernel_launch(void* const* d_in, const int* in_sizes, int n_in,
                              void* d_out, int out_size, void* d_ws, size_t ws_size,
                              hipStream_t stream) {
    const float* x = (const float*)d_in[0];
    // d_in[1] is m (ignored: missing_aware=False)
    const float* W = (const float*)d_in[2];
    float* out = (float*)d_out;

    int B = in_sizes[0] / DDIM;            // 4096
    unsigned* bm = (unsigned*)d_ws;        // 8 KB of workspace

    // Kernel 1: 2048 threads = 8 blocks x 256
    hipLaunchKernelGGL(binarize_pack_kernel, dim3(8), dim3(256), 0, stream, W, bm);

    // Kernel 2: 4 rows per block (4 waves x 64 lanes)
    int nblocks = (B + 3) / 4;
    hipLaunchKernelGGL(conj_forward_kernel, dim3(nblocks), dim3(256), 0, stream,
                       x, bm, out, B);
}